// Round 1
// baseline (2395.840 us; speedup 1.0000x reference)
//
#include <hip/hip_runtime.h>

#define KB 8
#define KN 4096
#define KNA 64
#define KH 12
#define KD 32
#define KC 384
#define KC2 768
#define KSCALE 0.17677669529663688f

// ---------------- K0: Kag = agent@Wk_ag + bk ; Qa = agent@Wq_ag + bq  (rows 512, cols 768)
__global__ __launch_bounds__(256) void k_agent_proj(
    const float* __restrict__ agent,
    const float* __restrict__ Wk_ag, const float* __restrict__ bk_ag,
    const float* __restrict__ Wq_ag, const float* __restrict__ bq_ag,
    float* __restrict__ Kag, float* __restrict__ Qa)
{
    __shared__ float a_lds[8][KC];
    const int tid = threadIdx.x;
    const int rg  = blockIdx.x;                    // 8-row group (64 groups)
    const float* W    = blockIdx.y ? Wq_ag : Wk_ag;
    const float* bias = blockIdx.y ? bq_ag : bk_ag;
    float* dst        = blockIdx.y ? Qa    : Kag;

    const float4* src4 = reinterpret_cast<const float4*>(agent) + (size_t)rg * 768;
    float4* al4 = reinterpret_cast<float4*>(&a_lds[0][0]);
    #pragma unroll
    for (int l = 0; l < 3; ++l) al4[tid + l*256] = src4[tid + l*256];
    __syncthreads();

    float acc[8][3] = {};
    for (int c = 0; c < KC; ++c) {
        float w0 = W[(size_t)c*KC2 + tid];
        float w1 = W[(size_t)c*KC2 + tid + 256];
        float w2 = W[(size_t)c*KC2 + tid + 512];
        #pragma unroll
        for (int r = 0; r < 8; ++r) {
            float a = a_lds[r][c];
            acc[r][0] = fmaf(a, w0, acc[r][0]);
            acc[r][1] = fmaf(a, w1, acc[r][1]);
            acc[r][2] = fmaf(a, w2, acc[r][2]);
        }
    }
    float b0 = bias[tid], b1 = bias[tid+256], b2 = bias[tid+512];
    #pragma unroll
    for (int r = 0; r < 8; ++r) {
        size_t base = (size_t)(rg*8 + r) * KC2;
        dst[base + tid      ] = acc[r][0] + b0;
        dst[base + tid + 256] = acc[r][1] + b1;
        dst[base + tid + 512] = acc[r][2] + b2;
    }
}

// ---------------- K2a: transpose Wk_hf [384,768] -> WkT [768,384]
__global__ __launch_bounds__(256) void k_transpose(
    const float* __restrict__ Win, float* __restrict__ Wout)
{
    __shared__ float tile[32][33];
    const int tx = threadIdx.x, ty = threadIdx.y;  // 32 x 8
    const int j0 = blockIdx.x * 32, c0 = blockIdx.y * 32;
    #pragma unroll
    for (int yy = 0; yy < 4; ++yy)
        tile[ty + yy*8][tx] = Win[(size_t)(c0 + ty + yy*8)*KC2 + j0 + tx];
    __syncthreads();
    #pragma unroll
    for (int yy = 0; yy < 4; ++yy)
        Wout[(size_t)(j0 + ty + yy*8)*KC + c0 + tx] = tile[tx][ty + yy*8];
}

// ---------------- K1: E[b][c][hm] = s0*sum_d Wq[c][h*32+d]*Kag[b][m][h*32+d]
//                                  + s1*sum_d Wq[c][384+h*32+d]*Kag[b][m][384+h*32+d]
__global__ __launch_bounds__(256) void k_build_E(
    const float* __restrict__ Wq_lf, const float* __restrict__ Kag,
    const float* __restrict__ wa, float* __restrict__ E)
{
    __shared__ float w_lds[8][KC2];
    const int tid = threadIdx.x;
    const int cg = blockIdx.x;   // 0..47 (8 c-rows each)
    const int b  = blockIdx.y;
    const float4* src = reinterpret_cast<const float4*>(Wq_lf + (size_t)cg*8*KC2);
    float4* dst4 = reinterpret_cast<float4*>(&w_lds[0][0]);
    #pragma unroll
    for (int l = 0; l < 6; ++l) dst4[tid + l*256] = src[tid + l*256];
    __syncthreads();
    const float s0 = KSCALE * wa[0], s1 = KSCALE * wa[1];
    float acc[8][3] = {};
    #pragma unroll
    for (int j = 0; j < 3; ++j) {
        const int hm = tid + j*256;
        const int h = hm >> 6, m = hm & 63;
        const float* kp = Kag + (size_t)(b*KNA + m)*KC2;
        const int base1 = h*KD, base2 = KC + h*KD;
        for (int d = 0; d < KD; ++d) {
            float a1 = kp[base1 + d] * s0;
            float a2 = kp[base2 + d] * s1;
            #pragma unroll
            for (int cr = 0; cr < 8; ++cr)
                acc[cr][j] += w_lds[cr][base1+d]*a1 + w_lds[cr][base2+d]*a2;
        }
    }
    #pragma unroll
    for (int cr = 0; cr < 8; ++cr)
        #pragma unroll
        for (int j = 0; j < 3; ++j)
            E[((size_t)b*KC + cg*8 + cr)*KC2 + tid + j*256] = acc[cr][j];
}

// ---------------- K2b: F[b][hm][c] = t0*sum_d Wk_hf[c][h*32+d]*Qa[b][m][h*32+d] + t1*(...384+...)
__global__ __launch_bounds__(128) void k_build_F(
    const float* __restrict__ WkT, const float* __restrict__ Qa,
    const float* __restrict__ wb, float* __restrict__ F)
{
    __shared__ float q_lds[8][64];
    const int tid = threadIdx.x;   // 128
    const int g = blockIdx.x;      // 0..95 (8 hm each)
    const int b = blockIdx.y;
    const int h = (g*8) >> 6;
    const float t0 = KSCALE*wb[0], t1 = KSCALE*wb[1];
    #pragma unroll
    for (int l = 0; l < 4; ++l) {
        int v = tid + l*128;
        int i = v >> 6, d = v & 63;
        int m = (g*8 + i) & 63;
        int jj   = (d < KD) ? (h*KD + d) : (KC + h*KD + d - KD);
        float cf = (d < KD) ? t0 : t1;
        q_lds[i][d] = cf * Qa[(size_t)(b*KNA + m)*KC2 + jj];
    }
    __syncthreads();
    float acc[8][3] = {};
    for (int d = 0; d < 64; ++d) {
        int row = (d < KD) ? (h*KD + d) : (KC + h*KD + d - KD);
        const float* wr = WkT + (size_t)row*KC;
        float w0 = wr[tid], w1 = wr[tid+128], w2 = wr[tid+256];
        #pragma unroll
        for (int i = 0; i < 8; ++i) {
            float q = q_lds[i][d];
            acc[i][0] = fmaf(q, w0, acc[i][0]);
            acc[i][1] = fmaf(q, w1, acc[i][1]);
            acc[i][2] = fmaf(q, w2, acc[i][2]);
        }
    }
    #pragma unroll
    for (int i = 0; i < 8; ++i)
        #pragma unroll
        for (int l = 0; l < 3; ++l)
            F[((size_t)b*KC2 + g*8 + i)*KC + tid + l*128] = acc[i][l];
}

// ---------------- K1c: bias constants cA, cB
__global__ __launch_bounds__(256) void k_build_c(
    const float* __restrict__ bq_lf, const float* __restrict__ Kag,
    const float* __restrict__ wa, const float* __restrict__ ba,
    const float* __restrict__ bk_hf, const float* __restrict__ Qa,
    const float* __restrict__ wb, const float* __restrict__ bbv,
    float* __restrict__ cA, float* __restrict__ cB)
{
    const int b = blockIdx.x;
    const float s0 = KSCALE*wa[0], s1 = KSCALE*wa[1];
    const float t0 = KSCALE*wb[0], t1 = KSCALE*wb[1];
    for (int hm = threadIdx.x; hm < KC2; hm += 256) {
        int h = hm >> 6, m = hm & 63;
        const float* kp = Kag + (size_t)(b*KNA + m)*KC2;
        const float* qp = Qa  + (size_t)(b*KNA + m)*KC2;
        float a = 0.f, bb2 = 0.f;
        for (int d = 0; d < KD; ++d) {
            a   += s0*bq_lf[h*KD+d]*kp[h*KD+d] + s1*bq_lf[KC+h*KD+d]*kp[KC+h*KD+d];
            bb2 += t0*bk_hf[h*KD+d]*qp[h*KD+d] + t1*bk_hf[KC+h*KD+d]*qp[KC+h*KD+d];
        }
        cA[(size_t)b*KC2 + hm] = a   + ba[0];
        cB[(size_t)b*KC2 + hm] = bb2 + bbv[0];
    }
}

// ---------------- K3: branch-B flash: per (b,h,chunk): t = F@attn^T + cB, e = exp(t),
//                 lpart = rowsum(e), Upart = e @ attn
__global__ __launch_bounds__(256, 1) void k_flash(
    const float* __restrict__ F, const float* __restrict__ cB,
    const float* __restrict__ attn,
    float* __restrict__ Upart, float* __restrict__ lpart,
    int nchunk, int NK)
{
    extern __shared__ float smem[];
    float* A_lds = smem;                  // [64][388]
    float* f_lds = A_lds + 64*388;        // [64][68]
    float* p_lds = f_lds + 64*68;         // [64][68]
    float* red   = p_lds + 64*68;         // [64][16]

    const int tid = threadIdx.x;
    const int tx = tid & 15, ty = tid >> 4;
    const int chunk = blockIdx.x, h = blockIdx.y, b = blockIdx.z;
    const int n0 = chunk * NK;
    const int NT = NK >> 6;

    float cBr[4];
    #pragma unroll
    for (int i = 0; i < 4; ++i) cBr[i] = cB[(size_t)b*KC2 + h*64 + i*16 + ty];

    float Uacc[4][24] = {};
    float lacc[4] = {};

    for (int nt = 0; nt < NT; ++nt) {
        __syncthreads();   // protect A_lds / p_lds from previous PV
        {   // load attn tile [64][384]
            int n = tid >> 2, c0 = (tid & 3)*96;
            const float4* src = reinterpret_cast<const float4*>(
                attn + (size_t)(b*KN + n0 + nt*64 + n)*KC + c0);
            float4* d4 = reinterpret_cast<float4*>(A_lds + n*388 + c0);
            #pragma unroll
            for (int q = 0; q < 24; ++q) d4[q] = src[q];
        }
        float tacc[4][4] = {};
        for (int kt = 0; kt < 6; ++kt) {
            if (kt) __syncthreads();
            {   // load F k-tile [64][64]
                int r = tid >> 2, k0 = (tid & 3)*16;
                const float4* src = reinterpret_cast<const float4*>(
                    F + (size_t)(b*KC2 + h*64 + r)*KC + kt*64 + k0);
                float4* d4 = reinterpret_cast<float4*>(f_lds + r*68 + k0);
                #pragma unroll
                for (int q = 0; q < 4; ++q) d4[q] = src[q];
            }
            __syncthreads();
            #pragma unroll 4
            for (int k = 0; k < 64; ++k) {
                float fv[4], av[4];
                #pragma unroll
                for (int i = 0; i < 4; ++i) fv[i] = f_lds[(i*16+ty)*68 + k];
                #pragma unroll
                for (int j = 0; j < 4; ++j) av[j] = A_lds[(j*16+tx)*388 + kt*64 + k];
                #pragma unroll
                for (int i = 0; i < 4; ++i)
                    #pragma unroll
                    for (int j = 0; j < 4; ++j)
                        tacc[i][j] = fmaf(fv[i], av[j], tacc[i][j]);
            }
        }
        // exp + write P + row-sum partials
        #pragma unroll
        for (int i = 0; i < 4; ++i)
            #pragma unroll
            for (int j = 0; j < 4; ++j) {
                float e = expf(tacc[i][j] + cBr[i]);
                p_lds[(i*16+ty)*68 + j*16+tx] = e;
                lacc[i] += e;
            }
        __syncthreads();
        // PV: Uacc += P @ A
        #pragma unroll 2
        for (int k = 0; k < 64; ++k) {
            float pv[4];
            #pragma unroll
            for (int i = 0; i < 4; ++i) pv[i] = p_lds[(i*16+ty)*68 + k];
            const float* arow = A_lds + k*388;
            #pragma unroll
            for (int cc = 0; cc < 24; ++cc) {
                float mv = arow[cc*16 + tx];
                #pragma unroll
                for (int i = 0; i < 4; ++i)
                    Uacc[i][cc] = fmaf(pv[i], mv, Uacc[i][cc]);
            }
        }
    }
    // write partial U
    #pragma unroll
    for (int i = 0; i < 4; ++i) {
        size_t base = ((size_t)((b*KH + h)*nchunk + chunk)*64 + i*16+ty)*KC;
        #pragma unroll
        for (int cc = 0; cc < 24; ++cc)
            Upart[base + cc*16 + tx] = Uacc[i][cc];
    }
    // reduce row sums
    #pragma unroll
    for (int i = 0; i < 4; ++i) red[(i*16+ty)*16 + tx] = lacc[i];
    __syncthreads();
    if (tid < 64) {
        float s = 0.f;
        #pragma unroll
        for (int t = 0; t < 16; ++t) s += red[tid*16 + t];
        lpart[(size_t)(b*KC2 + h*64 + tid)*nchunk + chunk] = s;
    }
}

// ---------------- K4: combine partials -> U (normalized) -> x_s -> M
__global__ __launch_bounds__(128) void k_combine(
    const float* __restrict__ Upart, const float* __restrict__ lpart,
    const float* __restrict__ Wv_hf, const float* __restrict__ bv_hf,
    const float* __restrict__ Wproj, float* __restrict__ M, int nchunk)
{
    __shared__ float u_lds[KC];
    __shared__ float xs_lds[KD];
    const int hm = blockIdx.x, b = blockIdx.y;
    const int h = hm >> 6;
    const int tid = threadIdx.x;
    float lsum = 0.f;
    for (int ch = 0; ch < nchunk; ++ch)
        lsum += lpart[(size_t)(b*KC2 + hm)*nchunk + ch];
    const float inv = 1.f / lsum;
    #pragma unroll
    for (int l = 0; l < 3; ++l) {
        int c = tid + l*128;
        float u = 0.f;
        for (int ch = 0; ch < nchunk; ++ch)
            u += Upart[((size_t)((b*KH + h)*nchunk + ch)*64 + (hm & 63))*KC + c];
        u_lds[c] = u * inv;
    }
    __syncthreads();
    if (tid < KD) {
        float acc = bv_hf[h*KD + tid];
        for (int c = 0; c < KC; ++c)
            acc = fmaf(u_lds[c], Wv_hf[(size_t)c*KC + h*KD + tid], acc);
        xs_lds[tid] = acc;
    }
    __syncthreads();
    #pragma unroll
    for (int l = 0; l < 3; ++l) {
        int e = tid + l*128;
        float acc = 0.f;
        #pragma unroll
        for (int d = 0; d < KD; ++d)
            acc = fmaf(xs_lds[d], Wproj[(size_t)(h*KD + d)*KC + e], acc);
        M[((size_t)b*KC2 + hm)*KC + e] = acc;
    }
}

// ---------------- K5: out = blocksoftmax(x@E + cA) @ M + bproj  (fused, per 64-row tile)
__global__ __launch_bounds__(256, 1) void k_out(
    const float* __restrict__ x, const float* __restrict__ E,
    const float* __restrict__ cA, const float* __restrict__ Mmat,
    const float* __restrict__ bproj, float* __restrict__ out)
{
    extern __shared__ float smem[];
    float* x_kt  = smem;                 // [64][68]
    float* e_kt  = x_kt + 64*68;         // [64][68]
    float* p_lds = e_kt + 64*68;         // [64][68]
    float* m_t   = p_lds + 64*68;        // [64][384]
    float* red   = m_t + 64*384;         // [64][16]
    float* invs  = red + 64*16;          // [64]

    const int tid = threadIdx.x;
    const int tx = tid & 15, ty = tid >> 4;
    const int nb = blockIdx.x, b = blockIdx.y;

    float oacc[4][24] = {};

    for (int h = 0; h < KH; ++h) {
        float tacc[4][4] = {};
        for (int kt = 0; kt < 6; ++kt) {
            __syncthreads();   // prev reads of x_kt/e_kt done (also PV of prev head done)
            {
                int r = tid >> 2, k0 = (tid & 3)*16;
                const float4* xs = reinterpret_cast<const float4*>(
                    x + (size_t)(b*KN + nb*64 + r)*KC + kt*64 + k0);
                float4* xd = reinterpret_cast<float4*>(x_kt + r*68 + k0);
                #pragma unroll
                for (int q = 0; q < 4; ++q) xd[q] = xs[q];
                const float4* es = reinterpret_cast<const float4*>(
                    E + (size_t)(b*KC + kt*64 + r)*KC2 + h*64 + k0);
                float4* ed = reinterpret_cast<float4*>(e_kt + r*68 + k0);
                #pragma unroll
                for (int q = 0; q < 4; ++q) ed[q] = es[q];
            }
            __syncthreads();
            #pragma unroll 4
            for (int k = 0; k < 64; ++k) {
                float xv[4], ev[4];
                #pragma unroll
                for (int i = 0; i < 4; ++i) xv[i] = x_kt[(i*16+ty)*68 + k];
                #pragma unroll
                for (int j = 0; j < 4; ++j) ev[j] = e_kt[k*68 + j*16 + tx];
                #pragma unroll
                for (int i = 0; i < 4; ++i)
                    #pragma unroll
                    for (int j = 0; j < 4; ++j)
                        tacc[i][j] = fmaf(xv[i], ev[j], tacc[i][j]);
            }
        }
        float cav[4];
        #pragma unroll
        for (int j = 0; j < 4; ++j) cav[j] = cA[(size_t)b*KC2 + h*64 + j*16 + tx];
        float rs[4] = {};
        #pragma unroll
        for (int i = 0; i < 4; ++i)
            #pragma unroll
            for (int j = 0; j < 4; ++j) {
                float e = expf(tacc[i][j] + cav[j]);
                p_lds[(i*16+ty)*68 + j*16+tx] = e;
                rs[i] += e;
            }
        #pragma unroll
        for (int i = 0; i < 4; ++i) red[(i*16+ty)*16 + tx] = rs[i];
        __syncthreads();   // P + red visible
        {   // load M tile while sums reduce
            int mm = tid >> 2, e0 = (tid & 3)*96;
            const float4* ms = reinterpret_cast<const float4*>(
                Mmat + (size_t)(b*KC2 + h*64 + mm)*KC + e0);
            float4* md = reinterpret_cast<float4*>(m_t + mm*384 + e0);
            #pragma unroll
            for (int q = 0; q < 24; ++q) md[q] = ms[q];
        }
        if (tid < 64) {
            float s = 0.f;
            #pragma unroll
            for (int t = 0; t < 16; ++t) s += red[tid*16 + t];
            invs[tid] = 1.f / s;
        }
        __syncthreads();
        float invr[4];
        #pragma unroll
        for (int i = 0; i < 4; ++i) invr[i] = invs[i*16 + ty];
        #pragma unroll 2
        for (int k = 0; k < 64; ++k) {
            float pv[4];
            #pragma unroll
            for (int i = 0; i < 4; ++i) pv[i] = p_lds[(i*16+ty)*68 + k] * invr[i];
            const float* mrow = m_t + k*384;
            #pragma unroll
            for (int cc = 0; cc < 24; ++cc) {
                float mv = mrow[cc*16 + tx];
                #pragma unroll
                for (int i = 0; i < 4; ++i)
                    oacc[i][cc] = fmaf(pv[i], mv, oacc[i][cc]);
            }
        }
    }
    // epilogue
    float bp[24];
    #pragma unroll
    for (int cc = 0; cc < 24; ++cc) bp[cc] = bproj[cc*16 + tx];
    #pragma unroll
    for (int i = 0; i < 4; ++i) {
        size_t base = (size_t)(b*KN + nb*64 + i*16 + ty)*KC;
        #pragma unroll
        for (int cc = 0; cc < 24; ++cc)
            out[base + cc*16 + tx] = oacc[i][cc] + bp[cc];
    }
}

extern "C" void kernel_launch(void* const* d_in, const int* in_sizes, int n_in,
                              void* d_out, int out_size, void* d_ws, size_t ws_size,
                              hipStream_t stream) {
    const float* x     = (const float*)d_in[0];
    const float* attn  = (const float*)d_in[1];
    const float* agent = (const float*)d_in[2];
    const float* Wq_lf = (const float*)d_in[3];
    const float* bq_lf = (const float*)d_in[4];
    const float* Wk_ag = (const float*)d_in[5];
    const float* bk_ag = (const float*)d_in[6];
    const float* wa    = (const float*)d_in[7];
    const float* ba    = (const float*)d_in[8];
    const float* Wq_ag = (const float*)d_in[9];
    const float* bq_ag = (const float*)d_in[10];
    const float* Wk_hf = (const float*)d_in[11];
    const float* bk_hf = (const float*)d_in[12];
    const float* Wv_hf = (const float*)d_in[13];
    const float* bv_hf = (const float*)d_in[14];
    const float* wb    = (const float*)d_in[15];
    const float* bb    = (const float*)d_in[16];
    const float* Wproj = (const float*)d_in[17];
    const float* bproj = (const float*)d_in[18];
    float* out = (float*)d_out;
    float* ws  = (float*)d_ws;

    // workspace layout (floats)
    const size_t o_Kag = 0;            // 393216
    const size_t o_Qa  = 393216;       // 393216
    const size_t o_E   = 786432;       // 2359296
    const size_t o_cA  = 3145728;      // 6144
    const size_t o_F   = 3151872;      // 2359296
    const size_t o_cB  = 5511168;      // 6144
    const size_t o_M   = 5517312;      // 2359296
    const size_t o_WkT = 7876608;      // 294912
    const size_t o_lp  = 8171520;      // 6144*nchunk
    int nchunk = 1;
    {
        const int cands[3] = {8, 4, 2};
        for (int ci = 0; ci < 3; ++ci) {
            size_t need = (8171520ull + 2365440ull * (size_t)cands[ci]) * 4ull;
            if (need <= ws_size) { nchunk = cands[ci]; break; }
        }
    }
    const size_t o_Up = o_lp + (size_t)6144 * nchunk;

    k_agent_proj<<<dim3(64, 2), 256, 0, stream>>>(agent, Wk_ag, bk_ag, Wq_ag, bq_ag,
                                                  ws + o_Kag, ws + o_Qa);
    k_transpose<<<dim3(24, 12), dim3(32, 8), 0, stream>>>(Wk_hf, ws + o_WkT);
    k_build_E<<<dim3(48, 8), 256, 0, stream>>>(Wq_lf, ws + o_Kag, wa, ws + o_E);
    k_build_F<<<dim3(96, 8), 128, 0, stream>>>(ws + o_WkT, ws + o_Qa, wb, ws + o_F);
    k_build_c<<<8, 256, 0, stream>>>(bq_lf, ws + o_Kag, wa, ba, bk_hf, ws + o_Qa,
                                     wb, bb, ws + o_cA, ws + o_cB);

    const int k3_lds = (64*388 + 64*68 + 64*68 + 64*16) * 4;          // 138240 B
    const int k5_lds = (64*68*3 + 64*384 + 64*16 + 64) * 4;           // 154880 B
    (void)hipFuncSetAttribute(reinterpret_cast<const void*>(k_flash),
                              hipFuncAttributeMaxDynamicSharedMemorySize, k3_lds);
    (void)hipFuncSetAttribute(reinterpret_cast<const void*>(k_out),
                              hipFuncAttributeMaxDynamicSharedMemorySize, k5_lds);

    k_flash<<<dim3(nchunk, KH, KB), 256, k3_lds, stream>>>(
        ws + o_F, ws + o_cB, attn, ws + o_Up, ws + o_lp, nchunk, KN / nchunk);
    k_combine<<<dim3(KC2, KB), 128, 0, stream>>>(
        ws + o_Up, ws + o_lp, Wv_hf, bv_hf, Wproj, ws + o_M, nchunk);
    k_out<<<dim3(KN / 64, KB), 256, k5_lds, stream>>>(
        x, ws + o_E, ws + o_cA, ws + o_M, bproj, out);
}

// Round 2
// 518.051 us; speedup vs baseline: 4.6247x; 4.6247x over previous
//
#include <hip/hip_runtime.h>

#define KB 8
#define KN 4096
#define KNA 64
#define KH 12
#define KD 32
#define KC 384
#define KC2 768
#define KSCALE 0.17677669529663688f

typedef __bf16 bf16x8 __attribute__((ext_vector_type(8)));
typedef float  f32x4  __attribute__((ext_vector_type(4)));

static __device__ __forceinline__ unsigned short f2bf(float f) {
    unsigned int u = __builtin_bit_cast(unsigned int, f);
    u += 0x7FFFu + ((u >> 16) & 1u);
    return (unsigned short)(u >> 16);
}

#define MFMA_16x16x32 __builtin_amdgcn_mfma_f32_16x16x32_bf16

// ---------------- K0: Kag = agent@Wk_ag + bk ; Qa = agent@Wq_ag + bq
__global__ __launch_bounds__(256) void k_agent_proj(
    const float* __restrict__ agent,
    const float* __restrict__ Wk_ag, const float* __restrict__ bk_ag,
    const float* __restrict__ Wq_ag, const float* __restrict__ bq_ag,
    float* __restrict__ Kag, float* __restrict__ Qa)
{
    __shared__ float a_lds[8][KC];
    const int tid = threadIdx.x;
    const int rg  = blockIdx.x;
    const float* W    = blockIdx.y ? Wq_ag : Wk_ag;
    const float* bias = blockIdx.y ? bq_ag : bk_ag;
    float* dst        = blockIdx.y ? Qa    : Kag;

    const float4* src4 = reinterpret_cast<const float4*>(agent) + (size_t)rg * 768;
    float4* al4 = reinterpret_cast<float4*>(&a_lds[0][0]);
    #pragma unroll
    for (int l = 0; l < 3; ++l) al4[tid + l*256] = src4[tid + l*256];
    __syncthreads();

    float acc[8][3] = {};
    for (int c = 0; c < KC; ++c) {
        float w0 = W[(size_t)c*KC2 + tid];
        float w1 = W[(size_t)c*KC2 + tid + 256];
        float w2 = W[(size_t)c*KC2 + tid + 512];
        #pragma unroll
        for (int r = 0; r < 8; ++r) {
            float a = a_lds[r][c];
            acc[r][0] = fmaf(a, w0, acc[r][0]);
            acc[r][1] = fmaf(a, w1, acc[r][1]);
            acc[r][2] = fmaf(a, w2, acc[r][2]);
        }
    }
    float b0 = bias[tid], b1 = bias[tid+256], b2 = bias[tid+512];
    #pragma unroll
    for (int r = 0; r < 8; ++r) {
        size_t base = (size_t)(rg*8 + r) * KC2;
        dst[base + tid      ] = acc[r][0] + b0;
        dst[base + tid + 256] = acc[r][1] + b1;
        dst[base + tid + 512] = acc[r][2] + b2;
    }
}

// ---------------- transpose Wk_hf [384,768] -> WkT [768,384] (f32)
__global__ __launch_bounds__(256) void k_transpose(
    const float* __restrict__ Win, float* __restrict__ Wout)
{
    __shared__ float tile[32][33];
    const int tx = threadIdx.x, ty = threadIdx.y;
    const int j0 = blockIdx.x * 32, c0 = blockIdx.y * 32;
    #pragma unroll
    for (int yy = 0; yy < 4; ++yy)
        tile[ty + yy*8][tx] = Win[(size_t)(c0 + ty + yy*8)*KC2 + j0 + tx];
    __syncthreads();
    #pragma unroll
    for (int yy = 0; yy < 4; ++yy)
        Wout[(size_t)(j0 + ty + yy*8)*KC + c0 + tx] = tile[tx][ty + yy*8];
}

// ---------------- generic transpose+cast: src f32 [R][C] -> dst bf16 [C][R], batched
__global__ __launch_bounds__(256) void k_tcast(
    const float* __restrict__ src, unsigned short* __restrict__ dst,
    int R, int C, long sstride, long dstride)
{
    __shared__ unsigned short lds[64][72];
    const int t = threadIdx.x;
    const int r0 = blockIdx.x * 64, c0 = blockIdx.y * 64;
    const float* s = src + (size_t)blockIdx.z * sstride;
    unsigned short* d = dst + (size_t)blockIdx.z * dstride;
    #pragma unroll
    for (int i = 0; i < 16; ++i) {
        int f = t + i*256; int rr = f >> 6, cc = f & 63;
        lds[rr][cc] = f2bf(s[(size_t)(r0+rr)*C + c0 + cc]);
    }
    __syncthreads();
    #pragma unroll
    for (int i = 0; i < 8; ++i) {
        int o = t + i*256; int c = o >> 5, n2 = (o & 31)*2;
        unsigned int v = (unsigned int)lds[n2][c] | ((unsigned int)lds[n2+1][c] << 16);
        *reinterpret_cast<unsigned int*>(d + (size_t)(c0 + c)*R + r0 + n2) = v;
    }
}

// ---------------- K1: E[b][c][hm]  (f32, for later transpose-cast)
__global__ __launch_bounds__(256) void k_build_E(
    const float* __restrict__ Wq_lf, const float* __restrict__ Kag,
    const float* __restrict__ wa, float* __restrict__ E)
{
    __shared__ float w_lds[8][KC2];
    const int tid = threadIdx.x;
    const int cg = blockIdx.x;
    const int b  = blockIdx.y;
    const float4* src = reinterpret_cast<const float4*>(Wq_lf + (size_t)cg*8*KC2);
    float4* dst4 = reinterpret_cast<float4*>(&w_lds[0][0]);
    #pragma unroll
    for (int l = 0; l < 6; ++l) dst4[tid + l*256] = src[tid + l*256];
    __syncthreads();
    const float s0 = KSCALE * wa[0], s1 = KSCALE * wa[1];
    float acc[8][3] = {};
    #pragma unroll
    for (int j = 0; j < 3; ++j) {
        const int hm = tid + j*256;
        const int h = hm >> 6, m = hm & 63;
        const float* kp = Kag + (size_t)(b*KNA + m)*KC2;
        const int base1 = h*KD, base2 = KC + h*KD;
        for (int d = 0; d < KD; ++d) {
            float a1 = kp[base1 + d] * s0;
            float a2 = kp[base2 + d] * s1;
            #pragma unroll
            for (int cr = 0; cr < 8; ++cr)
                acc[cr][j] += w_lds[cr][base1+d]*a1 + w_lds[cr][base2+d]*a2;
        }
    }
    #pragma unroll
    for (int cr = 0; cr < 8; ++cr)
        #pragma unroll
        for (int j = 0; j < 3; ++j)
            E[((size_t)b*KC + cg*8 + cr)*KC2 + tid + j*256] = acc[cr][j];
}

// ---------------- K2b: F_bf[b][hm][c] bf16
__global__ __launch_bounds__(128) void k_build_F(
    const float* __restrict__ WkT, const float* __restrict__ Qa,
    const float* __restrict__ wb, unsigned short* __restrict__ Fbf)
{
    __shared__ float q_lds[8][64];
    const int tid = threadIdx.x;
    const int g = blockIdx.x;
    const int b = blockIdx.y;
    const int h = (g*8) >> 6;
    const float t0 = KSCALE*wb[0], t1 = KSCALE*wb[1];
    #pragma unroll
    for (int l = 0; l < 4; ++l) {
        int v = tid + l*128;
        int i = v >> 6, d = v & 63;
        int m = (g*8 + i) & 63;
        int jj   = (d < KD) ? (h*KD + d) : (KC + h*KD + d - KD);
        float cf = (d < KD) ? t0 : t1;
        q_lds[i][d] = cf * Qa[(size_t)(b*KNA + m)*KC2 + jj];
    }
    __syncthreads();
    float acc[8][3] = {};
    for (int d = 0; d < 64; ++d) {
        int row = (d < KD) ? (h*KD + d) : (KC + h*KD + d - KD);
        const float* wr = WkT + (size_t)row*KC;
        float w0 = wr[tid], w1 = wr[tid+128], w2 = wr[tid+256];
        #pragma unroll
        for (int i = 0; i < 8; ++i) {
            float q = q_lds[i][d];
            acc[i][0] = fmaf(q, w0, acc[i][0]);
            acc[i][1] = fmaf(q, w1, acc[i][1]);
            acc[i][2] = fmaf(q, w2, acc[i][2]);
        }
    }
    #pragma unroll
    for (int i = 0; i < 8; ++i)
        #pragma unroll
        for (int l = 0; l < 3; ++l)
            Fbf[((size_t)b*KC2 + g*8 + i)*KC + tid + l*128] = f2bf(acc[i][l]);
}

// ---------------- K1c: bias constants cA, cB
__global__ __launch_bounds__(256) void k_build_c(
    const float* __restrict__ bq_lf, const float* __restrict__ Kag,
    const float* __restrict__ wa, const float* __restrict__ ba,
    const float* __restrict__ bk_hf, const float* __restrict__ Qa,
    const float* __restrict__ wb, const float* __restrict__ bbv,
    float* __restrict__ cA, float* __restrict__ cB)
{
    const int b = blockIdx.x;
    const float s0 = KSCALE*wa[0], s1 = KSCALE*wa[1];
    const float t0 = KSCALE*wb[0], t1 = KSCALE*wb[1];
    for (int hm = threadIdx.x; hm < KC2; hm += 256) {
        int h = hm >> 6, m = hm & 63;
        const float* kp = Kag + (size_t)(b*KNA + m)*KC2;
        const float* qp = Qa  + (size_t)(b*KNA + m)*KC2;
        float a = 0.f, bb2 = 0.f;
        for (int d = 0; d < KD; ++d) {
            a   += s0*bq_lf[h*KD+d]*kp[h*KD+d] + s1*bq_lf[KC+h*KD+d]*kp[KC+h*KD+d];
            bb2 += t0*bk_hf[h*KD+d]*qp[h*KD+d] + t1*bk_hf[KC+h*KD+d]*qp[KC+h*KD+d];
        }
        cA[(size_t)b*KC2 + hm] = a   + ba[0];
        cB[(size_t)b*KC2 + hm] = bb2 + bbv[0];
    }
}

// ---------------- K3: MFMA flash (branch B): per (h, chunk, b)
// LDS layout (bytes): a_rm [64][384] bf16 swizzled @0 (49152)
//                     a_T  [384][72] bf16 @49152 (55296)
//                     p    [64][72]  bf16 @104448 (9216)
//                     redl [2][64]   f32  @113664 (512)   total 114176
__global__ __launch_bounds__(512, 2) void k_flash2(
    const float* __restrict__ attn, const unsigned short* __restrict__ attnT,
    const unsigned short* __restrict__ Fbf, const float* __restrict__ cB,
    float* __restrict__ Upart, float* __restrict__ lpart,
    int nchunk, int NK)
{
    extern __shared__ char smem[];
    unsigned short* a_rm = (unsigned short*)smem;
    unsigned short* a_T  = (unsigned short*)(smem + 49152);
    unsigned short* p    = (unsigned short*)(smem + 104448);
    float*          redl = (float*)(smem + 113664);

    const int tid = threadIdx.x;
    const int wid = tid >> 6, lane = tid & 63;
    const int tx = lane & 15, ty = lane >> 4;
    const int h = blockIdx.x, chunk = blockIdx.y, b = blockIdx.z;
    const int n0 = chunk * NK;
    const int wn = wid >> 2, wh = wid & 3;     // QK^T roles
    const int uh = wid >> 2, wc = wid & 3;     // PV roles

    // preload F B-frags (12 k-steps) for this wave's 16 hm columns
    bf16x8 ffrag[12];
    {
        const unsigned short* fp = Fbf + ((size_t)(b*KC2 + h*64 + wh*16 + tx))*KC + ty*8;
        #pragma unroll
        for (int kk = 0; kk < 12; ++kk)
            ffrag[kk] = *reinterpret_cast<const bf16x8*>(fp + kk*32);
    }
    const float cbv = cB[(size_t)b*KC2 + h*64 + wh*16 + tx];
    float lacc = 0.f;
    f32x4 Uacc[2][6];
    #pragma unroll
    for (int i = 0; i < 2; ++i)
        #pragma unroll
        for (int j = 0; j < 6; ++j) Uacc[i][j] = (f32x4){0.f,0.f,0.f,0.f};

    const int NT = NK >> 6;
    for (int nt = 0; nt < NT; ++nt) {
        __syncthreads();   // prev PV reads of a_T/p done, a_rm free
        {   // stage a_rm (swizzled bf16) from f32 attn
            const float4* src = reinterpret_cast<const float4*>(
                attn + ((size_t)(b*KN + n0 + nt*64))*KC);
            #pragma unroll
            for (int i = 0; i < 12; ++i) {
                int f = tid + i*512;
                int n = f / 96, c4 = f % 96;
                float4 v = src[f];
                ushort4 h4 = { f2bf(v.x), f2bf(v.y), f2bf(v.z), f2bf(v.w) };
                int g = c4 >> 1, half = c4 & 1;
                int gs = g ^ (n & 7);
                *reinterpret_cast<ushort4*>(a_rm + n*384 + gs*8 + half*4) = h4;
            }
            // stage a_T from pre-transposed bf16 global
            const unsigned short* tsrc = attnT + (size_t)b*KC*KN + n0 + nt*64;
            #pragma unroll
            for (int i = 0; i < 6; ++i) {
                int ch = tid + i*512;
                int c = ch >> 3, g = ch & 7;
                bf16x8 v = *reinterpret_cast<const bf16x8*>(tsrc + (size_t)c*KN + g*8);
                *reinterpret_cast<bf16x8*>(a_T + c*72 + g*8) = v;
            }
        }
        __syncthreads();
        // QK^T (swapped): T'[n][hm] = attn_tile @ F^T
        f32x4 tacc[2];
        tacc[0] = (f32x4){0.f,0.f,0.f,0.f};
        tacc[1] = (f32x4){0.f,0.f,0.f,0.f};
        #pragma unroll
        for (int kk = 0; kk < 12; ++kk) {
            #pragma unroll
            for (int ns = 0; ns < 2; ++ns) {
                int n = wn*32 + ns*16 + tx;
                int g = kk*4 + ty;
                int gs = g ^ (n & 7);
                bf16x8 af = *reinterpret_cast<const bf16x8*>(a_rm + n*384 + gs*8);
                tacc[ns] = MFMA_16x16x32(af, ffrag[kk], tacc[ns], 0, 0, 0);
            }
        }
        // exp + lacc + pack P (bf16) into p[hm][n]
        #pragma unroll
        for (int ns = 0; ns < 2; ++ns) {
            float e0 = expf(tacc[ns][0] + cbv);
            float e1 = expf(tacc[ns][1] + cbv);
            float e2 = expf(tacc[ns][2] + cbv);
            float e3 = expf(tacc[ns][3] + cbv);
            lacc += e0 + e1 + e2 + e3;
            int hm = wh*16 + tx;
            int np = wn*32 + ns*16 + ty*4;
            ushort4 h4 = { f2bf(e0), f2bf(e1), f2bf(e2), f2bf(e3) };
            *reinterpret_cast<ushort4*>(p + hm*72 + np) = h4;
        }
        __syncthreads();
        // PV: Uacc += P @ attn_tile   (wave: [32 hm] x [96 c])
        #pragma unroll
        for (int ks = 0; ks < 2; ++ks) {
            bf16x8 pa[2];
            #pragma unroll
            for (int hs = 0; hs < 2; ++hs) {
                int hm = uh*32 + hs*16 + tx;
                pa[hs] = *reinterpret_cast<const bf16x8*>(p + hm*72 + ks*32 + ty*8);
            }
            #pragma unroll
            for (int cs = 0; cs < 6; ++cs) {
                int c = wc*96 + cs*16 + tx;
                bf16x8 bfv = *reinterpret_cast<const bf16x8*>(a_T + c*72 + ks*32 + ty*8);
                #pragma unroll
                for (int hs = 0; hs < 2; ++hs)
                    Uacc[hs][cs] = MFMA_16x16x32(pa[hs], bfv, Uacc[hs][cs], 0, 0, 0);
            }
        }
    }
    // epilogue: Upart (f32), lpart
    #pragma unroll
    for (int hs = 0; hs < 2; ++hs) {
        #pragma unroll
        for (int r = 0; r < 4; ++r) {
            int hm = uh*32 + hs*16 + ty*4 + r;
            size_t base = ((size_t)((b*KH + h)*nchunk + chunk)*64 + hm)*KC;
            #pragma unroll
            for (int cs = 0; cs < 6; ++cs)
                Upart[base + wc*96 + cs*16 + tx] = Uacc[hs][cs][r];
        }
    }
    lacc += __shfl_xor(lacc, 16);
    lacc += __shfl_xor(lacc, 32);
    if (lane < 16) redl[wn*64 + wh*16 + tx] = lacc;
    __syncthreads();
    if (tid < 64)
        lpart[((size_t)b*KC2 + h*64 + tid)*nchunk + chunk] = redl[tid] + redl[64 + tid];
}

// ---------------- K4: combine partials -> U (normalized) -> x_s -> M (f32)
__global__ __launch_bounds__(128) void k_combine(
    const float* __restrict__ Upart, const float* __restrict__ lpart,
    const float* __restrict__ Wv_hf, const float* __restrict__ bv_hf,
    const float* __restrict__ Wproj, float* __restrict__ M, int nchunk)
{
    __shared__ float u_lds[KC];
    __shared__ float xs_lds[KD];
    const int hm = blockIdx.x, b = blockIdx.y;
    const int h = hm >> 6;
    const int tid = threadIdx.x;
    float lsum = 0.f;
    for (int ch = 0; ch < nchunk; ++ch)
        lsum += lpart[(size_t)(b*KC2 + hm)*nchunk + ch];
    const float inv = 1.f / lsum;
    #pragma unroll
    for (int l = 0; l < 3; ++l) {
        int c = tid + l*128;
        float u = 0.f;
        for (int ch = 0; ch < nchunk; ++ch)
            u += Upart[((size_t)((b*KH + h)*nchunk + ch)*64 + (hm & 63))*KC + c];
        u_lds[c] = u * inv;
    }
    __syncthreads();
    if (tid < KD) {
        float acc = bv_hf[h*KD + tid];
        for (int c = 0; c < KC; ++c)
            acc = fmaf(u_lds[c], Wv_hf[(size_t)c*KC + h*KD + tid], acc);
        xs_lds[tid] = acc;
    }
    __syncthreads();
    #pragma unroll
    for (int l = 0; l < 3; ++l) {
        int e = tid + l*128;
        float acc = 0.f;
        #pragma unroll
        for (int d = 0; d < KD; ++d)
            acc = fmaf(xs_lds[d], Wproj[(size_t)(h*KD + d)*KC + e], acc);
        M[((size_t)b*KC2 + hm)*KC + e] = acc;
    }
}

// ---------------- K5: MFMA out: per (n-tile64, b), loop 12 heads
// LDS: xb [64][384] bf16 swz @0 (49152); mt [384][72] bf16 @49152 (55296);
//      p [64][72] bf16 @104448 (9216); red [4][64] f32 @113664 (1024);
//      invs [64] f32 @114688 (256); total 114944
__global__ __launch_bounds__(512, 2) void k_out2(
    const float* __restrict__ x, const unsigned short* __restrict__ Etbf,
    const float* __restrict__ cA, const unsigned short* __restrict__ Mtbf,
    const float* __restrict__ bproj, float* __restrict__ out)
{
    extern __shared__ char smem[];
    unsigned short* xb = (unsigned short*)smem;
    unsigned short* mt = (unsigned short*)(smem + 49152);
    unsigned short* p  = (unsigned short*)(smem + 104448);
    float* red  = (float*)(smem + 113664);
    float* invs = (float*)(smem + 114688);

    const int tid = threadIdx.x;
    const int wid = tid >> 6, lane = tid & 63;
    const int tx = lane & 15, ty = lane >> 4;
    const int nb = blockIdx.x, b = blockIdx.y;
    const int wn = wid >> 2, wm = wid & 3;     // QK^T roles
    const int un = wid >> 2, uc = wid & 3;     // PV roles

    f32x4 oacc[2][6];
    #pragma unroll
    for (int i = 0; i < 2; ++i)
        #pragma unroll
        for (int j = 0; j < 6; ++j) oacc[i][j] = (f32x4){0.f,0.f,0.f,0.f};

    {   // stage xb once (swizzled bf16 from f32 x)
        const float4* src = reinterpret_cast<const float4*>(
            x + ((size_t)(b*KN + nb*64))*KC);
        #pragma unroll
        for (int i = 0; i < 12; ++i) {
            int f = tid + i*512;
            int n = f / 96, c4 = f % 96;
            float4 v = src[f];
            ushort4 h4 = { f2bf(v.x), f2bf(v.y), f2bf(v.z), f2bf(v.w) };
            int g = c4 >> 1, half = c4 & 1;
            int gs = g ^ (n & 7);
            *reinterpret_cast<ushort4*>(xb + n*384 + gs*8 + half*4) = h4;
        }
    }

    for (int hh = 0; hh < KH; ++hh) {
        // preload E^T B-frags for this head (global, L2-hot)
        bf16x8 efrag[12];
        {
            const unsigned short* ep = Etbf + ((size_t)(b*KC2 + hh*64 + wm*16 + tx))*KC + ty*8;
            #pragma unroll
            for (int kk = 0; kk < 12; ++kk)
                efrag[kk] = *reinterpret_cast<const bf16x8*>(ep + kk*32);
        }
        const float cav = cA[(size_t)b*KC2 + hh*64 + wm*16 + tx];
        __syncthreads();   // (d): prev PV done -> mt/p/red writable; first iter: xb ready
        {   // stage mt = M^T for this head (bf16, [384][72])
            const unsigned int* msrc = reinterpret_cast<const unsigned int*>(
                Mtbf + (size_t)(b*KH + hh)*KC*64);
            #pragma unroll
            for (int i = 0; i < 12; ++i) {
                int ch = tid + i*512;
                int c = ch >> 4, g = ch & 15;
                uint2 v = *reinterpret_cast<const uint2*>(msrc + ch*2);
                *reinterpret_cast<uint2*>((char*)mt + c*144 + g*8) = v;
            }
        }
        // QK^T: L[n][m] = x_tile @ E_head
        f32x4 tacc[2];
        tacc[0] = (f32x4){0.f,0.f,0.f,0.f};
        tacc[1] = (f32x4){0.f,0.f,0.f,0.f};
        #pragma unroll
        for (int kk = 0; kk < 12; ++kk) {
            #pragma unroll
            for (int ns = 0; ns < 2; ++ns) {
                int n = wn*32 + ns*16 + tx;
                int g = kk*4 + ty;
                int gs = g ^ (n & 7);
                bf16x8 af = *reinterpret_cast<const bf16x8*>(xb + n*384 + gs*8);
                tacc[ns] = MFMA_16x16x32(af, efrag[kk], tacc[ns], 0, 0, 0);
            }
        }
        // exp + cross-wave row-sum (softmax over m)
        float e[2][4], s[2][4];
        #pragma unroll
        for (int ns = 0; ns < 2; ++ns)
            #pragma unroll
            for (int r = 0; r < 4; ++r) {
                e[ns][r] = expf(tacc[ns][r] + cav);
                s[ns][r] = e[ns][r];
            }
        #pragma unroll
        for (int mask = 1; mask < 16; mask <<= 1)
            #pragma unroll
            for (int ns = 0; ns < 2; ++ns)
                #pragma unroll
                for (int r = 0; r < 4; ++r)
                    s[ns][r] += __shfl_xor(s[ns][r], mask);
        if (tx == 0) {
            #pragma unroll
            for (int ns = 0; ns < 2; ++ns)
                #pragma unroll
                for (int r = 0; r < 4; ++r)
                    red[wm*64 + wn*32 + ns*16 + ty*4 + r] = s[ns][r];
        }
        __syncthreads();   // (a)
        if (tid < 64)
            invs[tid] = 1.f / (red[tid] + red[64+tid] + red[128+tid] + red[192+tid]);
        __syncthreads();   // (b)
        // normalized P -> bf16 p[n][m]
        #pragma unroll
        for (int ns = 0; ns < 2; ++ns)
            #pragma unroll
            for (int r = 0; r < 4; ++r) {
                int n = wn*32 + ns*16 + ty*4 + r;
                p[n*72 + wm*16 + tx] = f2bf(e[ns][r] * invs[n]);
            }
        __syncthreads();   // (c)
        // PV: oacc += P @ M^T  (wave: [32 n] x [96 c])
        #pragma unroll
        for (int ks = 0; ks < 2; ++ks) {
            bf16x8 pa[2];
            #pragma unroll
            for (int ns = 0; ns < 2; ++ns) {
                int n = un*32 + ns*16 + tx;
                pa[ns] = *reinterpret_cast<const bf16x8*>(p + n*72 + ks*32 + ty*8);
            }
            #pragma unroll
            for (int cs = 0; cs < 6; ++cs) {
                int c = uc*96 + cs*16 + tx;
                bf16x8 bfv = *reinterpret_cast<const bf16x8*>(mt + c*72 + ks*32 + ty*8);
                #pragma unroll
                for (int ns = 0; ns < 2; ++ns)
                    oacc[ns][cs] = MFMA_16x16x32(pa[ns], bfv, oacc[ns][cs], 0, 0, 0);
            }
        }
    }
    // epilogue
    float bp[6];
    #pragma unroll
    for (int cs = 0; cs < 6; ++cs) bp[cs] = bproj[uc*96 + cs*16 + tx];
    #pragma unroll
    for (int ns = 0; ns < 2; ++ns)
        #pragma unroll
        for (int r = 0; r < 4; ++r) {
            size_t base = (size_t)(b*KN + nb*64 + un*32 + ns*16 + ty*4 + r)*KC;
            #pragma unroll
            for (int cs = 0; cs < 6; ++cs)
                out[base + uc*96 + cs*16 + tx] = oacc[ns][cs][r] + bp[cs];
        }
}

extern "C" void kernel_launch(void* const* d_in, const int* in_sizes, int n_in,
                              void* d_out, int out_size, void* d_ws, size_t ws_size,
                              hipStream_t stream) {
    const float* x     = (const float*)d_in[0];
    const float* attn  = (const float*)d_in[1];
    const float* agent = (const float*)d_in[2];
    const float* Wq_lf = (const float*)d_in[3];
    const float* bq_lf = (const float*)d_in[4];
    const float* Wk_ag = (const float*)d_in[5];
    const float* bk_ag = (const float*)d_in[6];
    const float* wa    = (const float*)d_in[7];
    const float* ba    = (const float*)d_in[8];
    const float* Wq_ag = (const float*)d_in[9];
    const float* bq_ag = (const float*)d_in[10];
    const float* Wk_hf = (const float*)d_in[11];
    const float* bk_hf = (const float*)d_in[12];
    const float* Wv_hf = (const float*)d_in[13];
    const float* bv_hf = (const float*)d_in[14];
    const float* wb    = (const float*)d_in[15];
    const float* bb    = (const float*)d_in[16];
    const float* Wproj = (const float*)d_in[17];
    const float* bproj = (const float*)d_in[18];
    float* out = (float*)d_out;
    float* ws  = (float*)d_ws;

    // workspace layout (f32 units)
    const size_t o_Kag  = 0;          // 393216
    const size_t o_Qa   = 393216;     // 393216
    const size_t o_E    = 786432;     // 2359296
    const size_t o_cA   = 3145728;    // 6144
    const size_t o_Fbf  = 3151872;    // 1179648 (bf16 x 2359296)
    const size_t o_cB   = 4331520;    // 6144
    const size_t o_M    = 4337664;    // 2359296
    const size_t o_WkT  = 6696960;    // 294912
    const size_t o_Etbf = 6991872;    // 1179648 (bf16)
    const size_t o_Mtbf = 8171520;    // 1179648 (bf16)
    const size_t o_Tbf  = 9351168;    // 6291456 (bf16 x 12582912)
    const size_t o_lp_base = 15642624;

    int nchunk = 1;
    {
        const int cands[4] = {8, 4, 2, 1};
        for (int ci = 0; ci < 4; ++ci) {
            size_t need = (o_lp_base + (size_t)(6144 + 2359296) * cands[ci]) * 4ull;
            if (need <= ws_size) { nchunk = cands[ci]; break; }
        }
    }
    const size_t o_lp = o_lp_base;
    const size_t o_Up = o_lp + (size_t)6144 * nchunk;

    unsigned short* Fbf  = (unsigned short*)(ws + o_Fbf);
    unsigned short* Etbf = (unsigned short*)(ws + o_Etbf);
    unsigned short* Mtbf = (unsigned short*)(ws + o_Mtbf);
    unsigned short* Tbf  = (unsigned short*)(ws + o_Tbf);

    k_agent_proj<<<dim3(64, 2), 256, 0, stream>>>(agent, Wk_ag, bk_ag, Wq_ag, bq_ag,
                                                  ws + o_Kag, ws + o_Qa);
    k_transpose<<<dim3(24, 12), dim3(32, 8), 0, stream>>>(Wk_hf, ws + o_WkT);
    k_build_E<<<dim3(48, 8), 256, 0, stream>>>(Wq_lf, ws + o_Kag, wa, ws + o_E);
    // E [384][768] -> Et_bf [768][384] per b
    k_tcast<<<dim3(6, 12, 8), 256, 0, stream>>>(ws + o_E, Etbf, KC, KC2,
                                                (long)KC*KC2, (long)KC*KC2);
    k_build_F<<<dim3(96, 8), 128, 0, stream>>>(ws + o_WkT, ws + o_Qa, wb, Fbf);
    k_build_c<<<8, 256, 0, stream>>>(bq_lf, ws + o_Kag, wa, ba, bk_hf, ws + o_Qa,
                                     wb, bb, ws + o_cA, ws + o_cB);
    // attn [4096][384] -> T_bf [384][4096] per b
    k_tcast<<<dim3(64, 6, 8), 256, 0, stream>>>(attn, Tbf, KN, KC,
                                                (long)KN*KC, (long)KN*KC);

    const int fl_lds = 114176;
    const int ko_lds = 114944;
    (void)hipFuncSetAttribute(reinterpret_cast<const void*>(k_flash2),
                              hipFuncAttributeMaxDynamicSharedMemorySize, fl_lds);
    (void)hipFuncSetAttribute(reinterpret_cast<const void*>(k_out2),
                              hipFuncAttributeMaxDynamicSharedMemorySize, ko_lds);

    k_flash2<<<dim3(KH, nchunk, KB), 512, fl_lds, stream>>>(
        attn, Tbf, Fbf, ws + o_cB, ws + o_Up, ws + o_lp, nchunk, KN / nchunk);
    k_combine<<<dim3(KC2, KB), 128, 0, stream>>>(
        ws + o_Up, ws + o_lp, Wv_hf, bv_hf, Wproj, ws + o_M, nchunk);
    // M per (b,h): [64][384] -> Mt_bf [384][64]
    k_tcast<<<dim3(1, 6, 96), 256, 0, stream>>>(ws + o_M, Mtbf, 64, KC,
                                                (long)64*KC, (long)64*KC);
    k_out2<<<dim3(KN/64, KB), 512, ko_lds, stream>>>(
        x, Etbf, ws + o_cA, Mtbf, bproj, out);
}